// Round 1
// baseline (126.956 us; speedup 1.0000x reference)
//
#include <hip/hip_runtime.h>
#include <hip/hip_bf16.h>

// GAT layer: B=2, N=2048, C_IN=128, H=16, c=8.
// E(i,j) = exp(lrelu(lp_i+lc_j))*2^-12 = max(P1_i*Q1_j, P2_i*Q2_j)*adj  (f16).
// Aggregation: mfma_f32_16x16x32_f16; B-operand = [h feats | ones buffer].
// Round 15: occupancy push. Adjacency LDS tile stored as 0x00/0xFF BYTE masks
// (E*adj == E & mask, bit-exact for 0/1 adj); expanded per chunk via v_perm +
// v_and. i-tile halved to 16 rows -> grid 1024, LDS 40 KB (8 KB sAm + 32 KB
// sQ), 2-deep hQ prefetch, __launch_bounds__(512,6) -> target <=85 VGPR,
// 3 blocks/CU resident (24 waves/CU vs 16 at r14).
// d_out = [out: B*N*128][adj copy: B*N*N]

#define B_   2
#define N_   2048
#define CIN_ 128
#define H_   16

typedef _Float16 h2  __attribute__((ext_vector_type(2)));
typedef _Float16 v8h __attribute__((ext_vector_type(8)));
typedef float    v4f __attribute__((ext_vector_type(4)));

#define SC6 0.015625f   // 2^-6

__device__ inline h2 pk_f16(float a, float b) {
  return __builtin_bit_cast(h2, __builtin_amdgcn_cvt_pkrtz(a, b));
}
__device__ inline unsigned as_u32(h2 v) { return __builtin_bit_cast(unsigned, v); }
__device__ inline h2 as_h2(unsigned u) { return __builtin_bit_cast(h2, u); }

// 4 adjacency floats (exactly 0.0/1.0) -> 4 mask bytes 0x00/0xFF, j0 in byte0.
__device__ inline unsigned mask4(float4 f) {
  unsigned r = (unsigned)f.x | ((unsigned)f.y << 8) |
               ((unsigned)f.z << 16) | ((unsigned)f.w << 24);
  return (r << 8) - r;   // per-byte 0x01 -> 0xFF (no cross-byte borrow leak)
}

__global__ __launch_bounds__(128) void proj_kernel(
    const float* __restrict__ nf, const float* __restrict__ W,
    const float* __restrict__ bias, const float* __restrict__ a,
    unsigned* __restrict__ hQ, unsigned* __restrict__ qI,
    float* __restrict__ lpT, unsigned* __restrict__ ones) {
  const int row0 = blockIdx.x * 4;       // 4 consecutive rows (same batch)
  const int t    = threadIdx.x;          // output column 0..127
  if (blockIdx.x == 0) {                 // ones-buffer for B-operand cols 8..15
    ones[t] = 0x3C003C00u; ones[t + 128] = 0x3C003C00u;
    ones[t + 256] = 0x3C003C00u; ones[t + 384] = 0x3C003C00u;
  }
  __shared__ float sNf[4][CIN_];
  ((float4*)&sNf[0][0])[t] = ((const float4*)(nf + (long)row0 * CIN_))[t];
  __syncthreads();
  float acc[4];
  const float bv = bias[t];
#pragma unroll
  for (int r = 0; r < 4; ++r) acc[r] = bv;
#pragma unroll 8
  for (int k = 0; k < CIN_; ++k) {
    const float w = W[k * 128 + t];
#pragma unroll
    for (int r = 0; r < 4; ++r) acc[r] = fmaf(sNf[r][k], w, acc[r]);
  }
  const int h = t >> 3, kc = t & 7;
  const int b = row0 >> 11, n0 = row0 & (N_ - 1);
  const int bh = b * H_ + h;
  const int cdw = n0 >> 1;               // j-pair dword index (2-aligned)
  uint2 hv;
  hv.x = as_u32(pk_f16(acc[0], acc[1]));
  hv.y = as_u32(pk_f16(acc[2], acc[3]));
  *(uint2*)(hQ + ((long)(bh * 8 + kc)) * (N_ / 2) + cdw) = hv;

  const float ap = a[h * 16 + kc], ac = a[h * 16 + 8 + kc];
  float lpv[4], lcv[4];
#pragma unroll
  for (int r = 0; r < 4; ++r) {
    float x = acc[r] * ap, y = acc[r] * ac;
#pragma unroll
    for (int s = 1; s < 8; s <<= 1) {
      x += __shfl_xor(x, s);
      y += __shfl_xor(y, s);
    }
    lpv[r] = x; lcv[r] = y;
  }
  if (kc == 0) {
    float4 l0 = {lpv[0], lpv[1], lpv[2], lpv[3]};
    *(float4*)(lpT + (long)bh * N_ + n0) = l0;
    uint2 q1, q2;
    q1.x = as_u32(pk_f16(__expf(lcv[0]) * SC6, __expf(lcv[1]) * SC6));
    q1.y = as_u32(pk_f16(__expf(lcv[2]) * SC6, __expf(lcv[3]) * SC6));
    q2.x = as_u32(pk_f16(__expf(0.2f * lcv[0]) * SC6, __expf(0.2f * lcv[1]) * SC6));
    q2.y = as_u32(pk_f16(__expf(0.2f * lcv[2]) * SC6, __expf(0.2f * lcv[3]) * SC6));
    // interleave: chunk(16 pairs)=32dw: [q1 quad0|q2 quad0|...|q1 quad3|q2 quad3]
    const int addr = bh * 2048 + (cdw >> 4) * 32 + ((cdw >> 2) & 3) * 8;
    const int off  = cdw & 3;            // 0 or 2
    *(uint2*)(qI + addr + off)     = q1;
    *(uint2*)(qI + addr + 4 + off) = q2;
  }
}

__global__ __launch_bounds__(512, 6) void attn_kernel(
    const float* __restrict__ adj, const unsigned* __restrict__ hQ,
    const unsigned* __restrict__ qI, const float* __restrict__ lpT,
    const unsigned* __restrict__ ones, float* __restrict__ pA,
    float* __restrict__ pL, float* __restrict__ adj_out) {
  const int jq   = blockIdx.x & 3;       // j-quarter (512 wide)
  const int rest = blockIdx.x >> 2;
  const int b    = rest >> 7;            // 128 i-tiles (16-row) per batch
  const int i0   = (rest & 127) * 16;
  const int tid  = threadIdx.x;
  const int w    = tid >> 6;             // 0..7; wave = heads w and w+8
  const int lane = tid & 63;

  __shared__ uint2    sAm[1024];         // 8 KB: adj byte-mask, D=ch*64+q*16+m
  __shared__ unsigned sQ[8192];          // 32 KB: q1/q2 for 16 heads (qI layout)

  // ---- Stage sQ: thread t copies 16 dw of head (t>>5)'s j-quarter.
  {
    const int head = tid >> 5;
    const int off  = (tid & 31) * 16;
    const uint4* src = (const uint4*)(qI + (b * H_ + head) * 2048 + jq * 512 + off);
    uint4* dst = (uint4*)(sQ + head * 512 + off);
    dst[0] = src[0]; dst[1] = src[1]; dst[2] = src[2]; dst[3] = src[3];
  }
  // ---- Stage adjacency (f32 -> byte mask) + fused copy; loads hoisted.
  {
    const long aoff = (long)(b * N_ + i0) * N_ + jq * 512;
    const float* abase = adj + aoff;
    float* obase = adj_out + aoff;
    float4 fa[2], fb[2];
    int rowv[2], ccv[2];
#pragma unroll
    for (int s = 0; s < 2; ++s) {
      const int D = s * 512 + tid;
      const int mm = D & 15, qc = D >> 4;          // qc = ch*4+q, 0..63
      ccv[s] = (qc >> 2) * 32 + (qc & 3) * 8;
      rowv[s] = mm;
      fa[s] = *(const float4*)(abase + (long)mm * N_ + ccv[s]);
      fb[s] = *(const float4*)(abase + (long)mm * N_ + ccv[s] + 4);
    }
#pragma unroll
    for (int s = 0; s < 2; ++s) {
      const int D = s * 512 + tid;
      uint2 mv; mv.x = mask4(fa[s]); mv.y = mask4(fb[s]);
      sAm[D] = mv;
      *(float4*)(obase + (long)rowv[s] * N_ + ccv[s])     = fa[s];
      *(float4*)(obase + (long)rowv[s] * N_ + ccv[s] + 4) = fb[s];
    }
  }
  __syncthreads();

  const int m  = lane & 15;              // A row / B col / D col
  const int q  = lane >> 4;              // k-quad
  const int bh0 = b * H_ + w;            // head-group 0
  const int bh1 = bh0 + 8;               // head-group 1

  const float lp0 = lpT[(long)bh0 * N_ + i0 + m];
  const float lp1 = lpT[(long)bh1 * N_ + i0 + m];
  const float e10 = __expf(lp0) * SC6, e20 = __expf(0.2f * lp0) * SC6;
  const float e11 = __expf(lp1) * SC6, e21 = __expf(0.2f * lp1) * SC6;
  const h2 P10 = pk_f16(e10, e10), P20 = pk_f16(e20, e20);
  const h2 P11 = pk_f16(e11, e11), P21 = pk_f16(e21, e21);

  const unsigned* sq0 = sQ + w * 512 + q * 8;
  const unsigned* sq1 = sQ + (w + 8) * 512 + q * 8;
  const unsigned* hp0 = (m < 8)
      ? hQ + ((long)(bh0 * 8 + m)) * (N_ / 2) + jq * 256 + q * 4
      : ones + q * 4;
  const unsigned* hp1 = (m < 8)
      ? hQ + ((long)(bh1 * 8 + m)) * (N_ / 2) + jq * 256 + q * 4
      : ones + q * 4;

  v4f acc0 = {0.f, 0.f, 0.f, 0.f};       // head-group 0
  v4f acc1 = {0.f, 0.f, 0.f, 0.f};       // head-group 1

  // 2-deep prefetch of the only remaining global stream (hQ, L2-resident).
  uint4 h0[2], h1[2];
  h0[0] = *(const uint4*)(hp0);      h1[0] = *(const uint4*)(hp1);
  h0[1] = *(const uint4*)(hp0 + 16); h1[1] = *(const uint4*)(hp1 + 16);

  for (int t2 = 0; t2 < 8; ++t2) {
#pragma unroll
    for (int s = 0; s < 2; ++s) {
      const int ch = t2 * 2 + s;
      const int pf = ((ch + 2) & 15) * 16;
      const uint4 n0 = *(const uint4*)(hp0 + pf);
      const uint4 n1 = *(const uint4*)(hp1 + pf);

      const uint4 q1c0 = *(const uint4*)(sq0 + ch * 32);
      const uint4 q2c0 = *(const uint4*)(sq0 + ch * 32 + 4);
      const uint4 q1c1 = *(const uint4*)(sq1 + ch * 32);
      const uint4 q2c1 = *(const uint4*)(sq1 + ch * 32 + 4);

      // mask expansion: bytes [j3 j2 j1 j0] -> halfword masks per j-pair
      const uint2 Mv = sAm[ch * 64 + lane];
      const unsigned ma = __builtin_amdgcn_perm(Mv.x, Mv.x, 0x01010000u); // j0,j1
      const unsigned mb = __builtin_amdgcn_perm(Mv.x, Mv.x, 0x03030202u); // j2,j3
      const unsigned mc = __builtin_amdgcn_perm(Mv.y, Mv.y, 0x01010000u); // j4,j5
      const unsigned md = __builtin_amdgcn_perm(Mv.y, Mv.y, 0x03030202u); // j6,j7

      // head-group 0
      {
        const v8h bf = __builtin_bit_cast(v8h, h0[s]);
        const uint4 af = {
          as_u32(__builtin_elementwise_max(P10 * as_h2(q1c0.x), P20 * as_h2(q2c0.x))) & ma,
          as_u32(__builtin_elementwise_max(P10 * as_h2(q1c0.y), P20 * as_h2(q2c0.y))) & mb,
          as_u32(__builtin_elementwise_max(P10 * as_h2(q1c0.z), P20 * as_h2(q2c0.z))) & mc,
          as_u32(__builtin_elementwise_max(P10 * as_h2(q1c0.w), P20 * as_h2(q2c0.w))) & md};
        acc0 = __builtin_amdgcn_mfma_f32_16x16x32_f16(
            __builtin_bit_cast(v8h, af), bf, acc0, 0, 0, 0);
      }
      // head-group 1
      {
        const v8h bf = __builtin_bit_cast(v8h, h1[s]);
        const uint4 af = {
          as_u32(__builtin_elementwise_max(P11 * as_h2(q1c1.x), P21 * as_h2(q2c1.x))) & ma,
          as_u32(__builtin_elementwise_max(P11 * as_h2(q1c1.y), P21 * as_h2(q2c1.y))) & mb,
          as_u32(__builtin_elementwise_max(P11 * as_h2(q1c1.z), P21 * as_h2(q2c1.z))) & mc,
          as_u32(__builtin_elementwise_max(P11 * as_h2(q1c1.w), P21 * as_h2(q2c1.w))) & md};
        acc1 = __builtin_amdgcn_mfma_f32_16x16x32_f16(
            __builtin_bit_cast(v8h, af), bf, acc1, 0, 0, 0);
      }
      h0[s] = n0; h1[s] = n1;
    }
  }

  // D: col = lane&15, row = q*4 + reg. Write partials (no division).
#pragma unroll
  for (int g = 0; g < 2; ++g) {          // head-group
    const int hw = g * 8 + w;
    const v4f av = g ? acc1 : acc0;
#pragma unroll
    for (int r = 0; r < 4; ++r) {
      const int gidx = (b * N_ + i0 + q * 4 + r) * H_ + hw;
      if (m < 8)  pA[jq * 524288 + (long)gidx * 8 + m] = av[r];
      if (m == 8) pL[jq * 65536 + gidx] = av[r];
    }
  }
}

__global__ __launch_bounds__(512) void combine_kernel(
    const float* __restrict__ pA, const float* __restrict__ pL,
    float* __restrict__ out) {
  const int g = blockIdx.x * 512 + threadIdx.x;    // = ((b*N+i)*16+h)*8+k
  const int gl = g >> 3;
  const float s = pL[gl] + pL[gl + 65536] + pL[gl + 131072] + pL[gl + 196608];
  const float v = pA[g] + pA[g + 524288] + pA[g + 1048576] + pA[g + 1572864];
  out[g] = v / s;
}

extern "C" void kernel_launch(void* const* d_in, const int* in_sizes, int n_in,
                              void* d_out, int out_size, void* d_ws, size_t ws_size,
                              hipStream_t stream) {
  const float* nf   = (const float*)d_in[0];
  const float* adj  = (const float*)d_in[1];
  const float* W    = (const float*)d_in[2];
  const float* bias = (const float*)d_in[3];
  const float* a    = (const float*)d_in[4];

  float* out     = (float*)d_out;
  float* adj_out = out + (long)B_ * N_ * H_ * 8;    // 524288 offset

  unsigned* ws   = (unsigned*)d_ws;
  unsigned* hQ   = ws;                       // 262144 dw
  unsigned* qI   = ws + 262144;              // 65536 dw
  float*    lpT  = (float*)(ws + 327680);    // 65536 floats
  unsigned* ones = ws + 393216;              // 512 dw
  float*    pA   = (float*)(ws + 393728);    // 4 * 524288 floats
  float*    pL   = (float*)(ws + 2490880);   // 4 * 65536 floats

  hipLaunchKernelGGL(proj_kernel, dim3(B_ * N_ / 4), dim3(128), 0, stream,
                     nf, W, bias, a, hQ, qI, lpT, ones);
  hipLaunchKernelGGL(attn_kernel, dim3(B_ * (N_ / 16) * 4), dim3(512), 0,
                     stream, adj, hQ, qI, lpT, ones, pA, pL, adj_out);
  hipLaunchKernelGGL(combine_kernel, dim3(1024), dim3(512), 0, stream,
                     pA, pL, out);
}

// Round 2
// 125.574 us; speedup vs baseline: 1.0110x; 1.0110x over previous
//
#include <hip/hip_runtime.h>
#include <hip/hip_bf16.h>

// GAT layer: B=2, N=2048, C_IN=128, H=16, c=8.
// E(i,j) = exp(lrelu(lp_i+lc_j))*2^-12 = max(P1_i*Q1_j, P2_i*Q2_j)*adj  (f16).
// Aggregation: mfma_f32_16x16x32_f16; B-operand = [h feats | ones buffer].
// Round 16: r14 structure (32-row i-tiles: Q LDS reads amortized over 2
// i-subtiles -> 2 B per E-element) + r15 byte-mask adjacency (sAm 16 KB,
// b64 mask reads -> 0.5 B/el, E*adj == E & mask bit-exact for 0/1 adj).
// LDS/block 64 KB -> 48 KB; per-chunk LDS return bytes 6144 -> 5120.
// d_out = [out: B*N*128][adj copy: B*N*N]

#define B_   2
#define N_   2048
#define CIN_ 128
#define H_   16

typedef _Float16 h2  __attribute__((ext_vector_type(2)));
typedef _Float16 v8h __attribute__((ext_vector_type(8)));
typedef float    v4f __attribute__((ext_vector_type(4)));

#define SC6 0.015625f   // 2^-6

__device__ inline h2 pk_f16(float a, float b) {
  return __builtin_bit_cast(h2, __builtin_amdgcn_cvt_pkrtz(a, b));
}
__device__ inline unsigned as_u32(h2 v) { return __builtin_bit_cast(unsigned, v); }
__device__ inline h2 as_h2(unsigned u) { return __builtin_bit_cast(h2, u); }

// 4 adjacency floats (exactly 0.0/1.0) -> 4 mask bytes 0x00/0xFF, j0 in byte0.
__device__ inline unsigned mask4(float4 f) {
  unsigned r = (unsigned)f.x | ((unsigned)f.y << 8) |
               ((unsigned)f.z << 16) | ((unsigned)f.w << 24);
  return (r << 8) - r;   // per-byte 0x01 -> 0xFF
}

__global__ __launch_bounds__(128) void proj_kernel(
    const float* __restrict__ nf, const float* __restrict__ W,
    const float* __restrict__ bias, const float* __restrict__ a,
    unsigned* __restrict__ hQ, unsigned* __restrict__ qI,
    float* __restrict__ lpT, unsigned* __restrict__ ones) {
  const int row0 = blockIdx.x * 4;       // 4 consecutive rows (same batch)
  const int t    = threadIdx.x;          // output column 0..127
  if (blockIdx.x == 0) {                 // ones-buffer for B-operand cols 8..15
    ones[t] = 0x3C003C00u; ones[t + 128] = 0x3C003C00u;
    ones[t + 256] = 0x3C003C00u; ones[t + 384] = 0x3C003C00u;
  }
  __shared__ float sNf[4][CIN_];
  ((float4*)&sNf[0][0])[t] = ((const float4*)(nf + (long)row0 * CIN_))[t];
  __syncthreads();
  float acc[4];
  const float bv = bias[t];
#pragma unroll
  for (int r = 0; r < 4; ++r) acc[r] = bv;
#pragma unroll 8
  for (int k = 0; k < CIN_; ++k) {
    const float w = W[k * 128 + t];
#pragma unroll
    for (int r = 0; r < 4; ++r) acc[r] = fmaf(sNf[r][k], w, acc[r]);
  }
  const int h = t >> 3, kc = t & 7;
  const int b = row0 >> 11, n0 = row0 & (N_ - 1);
  const int bh = b * H_ + h;
  const int cdw = n0 >> 1;               // j-pair dword index (2-aligned)
  uint2 hv;
  hv.x = as_u32(pk_f16(acc[0], acc[1]));
  hv.y = as_u32(pk_f16(acc[2], acc[3]));
  *(uint2*)(hQ + ((long)(bh * 8 + kc)) * (N_ / 2) + cdw) = hv;

  const float ap = a[h * 16 + kc], ac = a[h * 16 + 8 + kc];
  float lpv[4], lcv[4];
#pragma unroll
  for (int r = 0; r < 4; ++r) {
    float x = acc[r] * ap, y = acc[r] * ac;
#pragma unroll
    for (int s = 1; s < 8; s <<= 1) {
      x += __shfl_xor(x, s);
      y += __shfl_xor(y, s);
    }
    lpv[r] = x; lcv[r] = y;
  }
  if (kc == 0) {
    float4 l0 = {lpv[0], lpv[1], lpv[2], lpv[3]};
    *(float4*)(lpT + (long)bh * N_ + n0) = l0;
    uint2 q1, q2;
    q1.x = as_u32(pk_f16(__expf(lcv[0]) * SC6, __expf(lcv[1]) * SC6));
    q1.y = as_u32(pk_f16(__expf(lcv[2]) * SC6, __expf(lcv[3]) * SC6));
    q2.x = as_u32(pk_f16(__expf(0.2f * lcv[0]) * SC6, __expf(0.2f * lcv[1]) * SC6));
    q2.y = as_u32(pk_f16(__expf(0.2f * lcv[2]) * SC6, __expf(0.2f * lcv[3]) * SC6));
    // interleave: chunk(16 pairs)=32dw: [q1 quad0|q2 quad0|...|q1 quad3|q2 quad3]
    const int addr = bh * 2048 + (cdw >> 4) * 32 + ((cdw >> 2) & 3) * 8;
    const int off  = cdw & 3;            // 0 or 2
    *(uint2*)(qI + addr + off)     = q1;
    *(uint2*)(qI + addr + 4 + off) = q2;
  }
}

__global__ __launch_bounds__(512) void attn_kernel(
    const float* __restrict__ adj, const unsigned* __restrict__ hQ,
    const unsigned* __restrict__ qI, const float* __restrict__ lpT,
    const unsigned* __restrict__ ones, float* __restrict__ pA,
    float* __restrict__ pL, float* __restrict__ adj_out) {
  const int jq   = blockIdx.x & 3;       // j-quarter (512 wide)
  const int rest = blockIdx.x >> 2;
  const int b    = rest >> 6;            // 64 i-tiles (32-row) per batch
  const int i0   = (rest & 63) * 32;
  const int tid  = threadIdx.x;
  const int w    = tid >> 6;             // 0..7; wave = heads w and w+8
  const int lane = tid & 63;

  __shared__ uint2    sAm[2048];         // 16 KB: adj byte-mask, D=u*1024+ch*64+q*16+m
  __shared__ unsigned sQ[8192];          // 32 KB: q1/q2 for 16 heads (qI layout)

  // ---- Stage sQ: thread t copies 16 dw of head (t>>5)'s j-quarter.
  {
    const int head = tid >> 5;
    const int off  = (tid & 31) * 16;
    const uint4* src = (const uint4*)(qI + (b * H_ + head) * 2048 + jq * 512 + off);
    uint4* dst = (uint4*)(sQ + head * 512 + off);
    dst[0] = src[0]; dst[1] = src[1]; dst[2] = src[2]; dst[3] = src[3];
  }
  // ---- Stage adjacency (f32 -> byte mask) + fused copy; loads hoisted.
  {
    const long aoff = (long)(b * N_ + i0) * N_ + jq * 512;
    const float* abase = adj + aoff;
    float* obase = adj_out + aoff;
    float4 fa[4], fb[4];
    int rowv[4], ccv[4];
#pragma unroll
    for (int s = 0; s < 4; ++s) {
      const int D = s * 512 + tid;
      const int u = D >> 10, loc = D & 1023;
      const int mm = loc & 15, qc = loc >> 4;
      ccv[s] = (qc >> 2) * 32 + (qc & 3) * 8;
      rowv[s] = u * 16 + mm;
      fa[s] = *(const float4*)(abase + (long)rowv[s] * N_ + ccv[s]);
      fb[s] = *(const float4*)(abase + (long)rowv[s] * N_ + ccv[s] + 4);
    }
#pragma unroll
    for (int s = 0; s < 4; ++s) {
      const int D = s * 512 + tid;
      uint2 mv; mv.x = mask4(fa[s]); mv.y = mask4(fb[s]);
      sAm[D] = mv;
      *(float4*)(obase + (long)rowv[s] * N_ + ccv[s])     = fa[s];
      *(float4*)(obase + (long)rowv[s] * N_ + ccv[s] + 4) = fb[s];
    }
  }
  __syncthreads();

  const int m  = lane & 15;              // A row / B col / D col
  const int q  = lane >> 4;              // k-quad
  const int bh0 = b * H_ + w;            // head-group 0
  const int bh1 = bh0 + 8;               // head-group 1

  const float lpa0 = lpT[(long)bh0 * N_ + i0 + m];
  const float lpb0 = lpT[(long)bh0 * N_ + i0 + 16 + m];
  const float lpa1 = lpT[(long)bh1 * N_ + i0 + m];
  const float lpb1 = lpT[(long)bh1 * N_ + i0 + 16 + m];
  const h2 P1a0 = pk_f16(__expf(lpa0) * SC6, __expf(lpa0) * SC6);
  const h2 P2a0 = pk_f16(__expf(0.2f * lpa0) * SC6, __expf(0.2f * lpa0) * SC6);
  const h2 P1b0 = pk_f16(__expf(lpb0) * SC6, __expf(lpb0) * SC6);
  const h2 P2b0 = pk_f16(__expf(0.2f * lpb0) * SC6, __expf(0.2f * lpb0) * SC6);
  const h2 P1a1 = pk_f16(__expf(lpa1) * SC6, __expf(lpa1) * SC6);
  const h2 P2a1 = pk_f16(__expf(0.2f * lpa1) * SC6, __expf(0.2f * lpa1) * SC6);
  const h2 P1b1 = pk_f16(__expf(lpb1) * SC6, __expf(lpb1) * SC6);
  const h2 P2b1 = pk_f16(__expf(0.2f * lpb1) * SC6, __expf(0.2f * lpb1) * SC6);

  const unsigned* sq0 = sQ + w * 512 + q * 8;
  const unsigned* sq1 = sQ + (w + 8) * 512 + q * 8;
  const unsigned* hp0 = (m < 8)
      ? hQ + ((long)(bh0 * 8 + m)) * (N_ / 2) + jq * 256 + q * 4
      : ones + q * 4;
  const unsigned* hp1 = (m < 8)
      ? hQ + ((long)(bh1 * 8 + m)) * (N_ / 2) + jq * 256 + q * 4
      : ones + q * 4;

  v4f acc0a = {0.f, 0.f, 0.f, 0.f}, acc1a = {0.f, 0.f, 0.f, 0.f};
  v4f acc0b = {0.f, 0.f, 0.f, 0.f}, acc1b = {0.f, 0.f, 0.f, 0.f};

  // 4-deep prefetch of the only remaining global stream (hQ, 2 head-groups).
  uint4 h0[4], h1[4];
#pragma unroll
  for (int d = 0; d < 4; ++d) {
    h0[d] = *(const uint4*)(hp0 + d * 16);
    h1[d] = *(const uint4*)(hp1 + d * 16);
  }

  for (int t4 = 0; t4 < 4; ++t4) {
#pragma unroll
    for (int s = 0; s < 4; ++s) {
      const int ch = t4 * 4 + s;
      const int pf = ((ch + 4) & 15) * 16;
      const uint4 n0 = *(const uint4*)(hp0 + pf);
      const uint4 n1 = *(const uint4*)(hp1 + pf);

      const uint4 q1c0 = *(const uint4*)(sq0 + ch * 32);
      const uint4 q2c0 = *(const uint4*)(sq0 + ch * 32 + 4);
      const uint4 q1c1 = *(const uint4*)(sq1 + ch * 32);
      const uint4 q2c1 = *(const uint4*)(sq1 + ch * 32 + 4);

      // mask expansion: bytes [j3 j2 j1 j0] -> halfword masks per j-pair
      const uint2 Mv0 = sAm[ch * 64 + lane];           // i-subtile 0
      const uint2 Mv1 = sAm[1024 + ch * 64 + lane];    // i-subtile 1
      const unsigned m0a = __builtin_amdgcn_perm(Mv0.x, Mv0.x, 0x01010000u);
      const unsigned m0b = __builtin_amdgcn_perm(Mv0.x, Mv0.x, 0x03030202u);
      const unsigned m0c = __builtin_amdgcn_perm(Mv0.y, Mv0.y, 0x01010000u);
      const unsigned m0d = __builtin_amdgcn_perm(Mv0.y, Mv0.y, 0x03030202u);
      const unsigned m1a = __builtin_amdgcn_perm(Mv1.x, Mv1.x, 0x01010000u);
      const unsigned m1b = __builtin_amdgcn_perm(Mv1.x, Mv1.x, 0x03030202u);
      const unsigned m1c = __builtin_amdgcn_perm(Mv1.y, Mv1.y, 0x01010000u);
      const unsigned m1d = __builtin_amdgcn_perm(Mv1.y, Mv1.y, 0x03030202u);

      // head-group 0
      {
        const h2 Q1x = as_h2(q1c0.x), Q1y = as_h2(q1c0.y), Q1z = as_h2(q1c0.z), Q1w = as_h2(q1c0.w);
        const h2 Q2x = as_h2(q2c0.x), Q2y = as_h2(q2c0.y), Q2z = as_h2(q2c0.z), Q2w = as_h2(q2c0.w);
        const v8h bf = __builtin_bit_cast(v8h, h0[s]);
        const uint4 af0 = {
          as_u32(__builtin_elementwise_max(P1a0 * Q1x, P2a0 * Q2x)) & m0a,
          as_u32(__builtin_elementwise_max(P1a0 * Q1y, P2a0 * Q2y)) & m0b,
          as_u32(__builtin_elementwise_max(P1a0 * Q1z, P2a0 * Q2z)) & m0c,
          as_u32(__builtin_elementwise_max(P1a0 * Q1w, P2a0 * Q2w)) & m0d};
        acc0a = __builtin_amdgcn_mfma_f32_16x16x32_f16(
            __builtin_bit_cast(v8h, af0), bf, acc0a, 0, 0, 0);
        const uint4 af1 = {
          as_u32(__builtin_elementwise_max(P1b0 * Q1x, P2b0 * Q2x)) & m1a,
          as_u32(__builtin_elementwise_max(P1b0 * Q1y, P2b0 * Q2y)) & m1b,
          as_u32(__builtin_elementwise_max(P1b0 * Q1z, P2b0 * Q2z)) & m1c,
          as_u32(__builtin_elementwise_max(P1b0 * Q1w, P2b0 * Q2w)) & m1d};
        acc1a = __builtin_amdgcn_mfma_f32_16x16x32_f16(
            __builtin_bit_cast(v8h, af1), bf, acc1a, 0, 0, 0);
      }
      // head-group 1
      {
        const h2 Q1x = as_h2(q1c1.x), Q1y = as_h2(q1c1.y), Q1z = as_h2(q1c1.z), Q1w = as_h2(q1c1.w);
        const h2 Q2x = as_h2(q2c1.x), Q2y = as_h2(q2c1.y), Q2z = as_h2(q2c1.z), Q2w = as_h2(q2c1.w);
        const v8h bf = __builtin_bit_cast(v8h, h1[s]);
        const uint4 af0 = {
          as_u32(__builtin_elementwise_max(P1a1 * Q1x, P2a1 * Q2x)) & m0a,
          as_u32(__builtin_elementwise_max(P1a1 * Q1y, P2a1 * Q2y)) & m0b,
          as_u32(__builtin_elementwise_max(P1a1 * Q1z, P2a1 * Q2z)) & m0c,
          as_u32(__builtin_elementwise_max(P1a1 * Q1w, P2a1 * Q2w)) & m0d};
        acc0b = __builtin_amdgcn_mfma_f32_16x16x32_f16(
            __builtin_bit_cast(v8h, af0), bf, acc0b, 0, 0, 0);
        const uint4 af1 = {
          as_u32(__builtin_elementwise_max(P1b1 * Q1x, P2b1 * Q2x)) & m1a,
          as_u32(__builtin_elementwise_max(P1b1 * Q1y, P2b1 * Q2y)) & m1b,
          as_u32(__builtin_elementwise_max(P1b1 * Q1z, P2b1 * Q2z)) & m1c,
          as_u32(__builtin_elementwise_max(P1b1 * Q1w, P2b1 * Q2w)) & m1d};
        acc1b = __builtin_amdgcn_mfma_f32_16x16x32_f16(
            __builtin_bit_cast(v8h, af1), bf, acc1b, 0, 0, 0);
      }
      h0[s] = n0; h1[s] = n1;
    }
  }

  // D: col = lane&15, row = q*4 + reg. Write partials (no division).
#pragma unroll
  for (int g = 0; g < 2; ++g) {          // head-group
    const int hw = g * 8 + w;
#pragma unroll
    for (int u = 0; u < 2; ++u) {        // i-subtile
      const v4f av = g ? (u ? acc1b : acc0b) : (u ? acc1a : acc0a);
#pragma unroll
      for (int r = 0; r < 4; ++r) {
        const int gidx = (b * N_ + i0 + u * 16 + q * 4 + r) * H_ + hw;
        if (m < 8)  pA[jq * 524288 + (long)gidx * 8 + m] = av[r];
        if (m == 8) pL[jq * 65536 + gidx] = av[r];
      }
    }
  }
}

__global__ __launch_bounds__(512) void combine_kernel(
    const float* __restrict__ pA, const float* __restrict__ pL,
    float* __restrict__ out) {
  const int g = blockIdx.x * 512 + threadIdx.x;    // = ((b*N+i)*16+h)*8+k
  const int gl = g >> 3;
  const float s = pL[gl] + pL[gl + 65536] + pL[gl + 131072] + pL[gl + 196608];
  const float v = pA[g] + pA[g + 524288] + pA[g + 1048576] + pA[g + 1572864];
  out[g] = v / s;
}

extern "C" void kernel_launch(void* const* d_in, const int* in_sizes, int n_in,
                              void* d_out, int out_size, void* d_ws, size_t ws_size,
                              hipStream_t stream) {
  const float* nf   = (const float*)d_in[0];
  const float* adj  = (const float*)d_in[1];
  const float* W    = (const float*)d_in[2];
  const float* bias = (const float*)d_in[3];
  const float* a    = (const float*)d_in[4];

  float* out     = (float*)d_out;
  float* adj_out = out + (long)B_ * N_ * H_ * 8;    // 524288 offset

  unsigned* ws   = (unsigned*)d_ws;
  unsigned* hQ   = ws;                       // 262144 dw
  unsigned* qI   = ws + 262144;              // 65536 dw
  float*    lpT  = (float*)(ws + 327680);    // 65536 floats
  unsigned* ones = ws + 393216;              // 512 dw
  float*    pA   = (float*)(ws + 393728);    // 4 * 524288 floats
  float*    pL   = (float*)(ws + 2490880);   // 4 * 65536 floats

  hipLaunchKernelGGL(proj_kernel, dim3(B_ * N_ / 4), dim3(128), 0, stream,
                     nf, W, bias, a, hQ, qI, lpT, ones);
  hipLaunchKernelGGL(attn_kernel, dim3(B_ * (N_ / 32) * 4), dim3(512), 0,
                     stream, adj, hQ, qI, lpT, ones, pA, pL, adj_out);
  hipLaunchKernelGGL(combine_kernel, dim3(1024), dim3(512), 0, stream,
                     pA, pL, out);
}